// Round 3
// baseline (219.655 us; speedup 1.0000x reference)
//
#include <hip/hip_runtime.h>
#include <math.h>

// Wave-per-ray formulation. Lane p owns: coarse point p, sample u=(p+1)/64, fine point p.
// Per-ray query is affine in depth (feat[c] = base[c] + d*slope[c]); sigmoid via
// rcp(1+exp2(arg)) with -log2e folded into the affine coefficients.
// Transmittance = wave prefix-product; CDF = wave prefix-sum (reuses coarse w -> no
// phase-2 sigmoids); searchsorted + merge-ranks = fixed-trip shuffle binary searches.
// Uniform control flow, zero LDS in the main kernel, 131072 waves (128/SIMD queued).

#define PTS 64
#define IMP 64
#define NRAYS (2*256*256)
#define STEPV (1.9f/63.0f)
#define NL2E (-1.4426950408889634f)

extern "C" __device__ float __ocml_native_exp2_f32(float);

__device__ __forceinline__ float sig_pm(float arg) {   // arg is already -x*log2e
    return __builtin_amdgcn_rcpf(1.0f + __ocml_native_exp2_f32(arg));
}

__device__ __forceinline__ float wave_sum(float v) {
    #pragma unroll
    for (int m = 32; m >= 1; m >>= 1) v += __shfl_xor(v, m, 64);
    return v;
}

__device__ __forceinline__ float scan_mul_incl(float v, int lane) {
    #pragma unroll
    for (int d = 1; d < 64; d <<= 1) {
        float o = __shfl_up(v, d, 64);
        if (lane >= d) v *= o;
    }
    return v;
}

__device__ __forceinline__ float scan_add_incl(float v, int lane) {
    #pragma unroll
    for (int d = 1; d < 64; d <<= 1) {
        float o = __shfl_up(v, d, 64);
        if (lane >= d) v += o;
    }
    return v;
}

__global__ __launch_bounds__(256) void nerf_main(
    const float* __restrict__ tm, const float* __restrict__ wq,
    float* __restrict__ out)
{
    const int lane = threadIdx.x & 63;
    const int r = blockIdx.x * 4 + (threadIdx.x >> 6);   // 4 rays (waves) per block
    const int b = r >> 16;
    const int n = r & 65535;
    const int i = n >> 8;
    const int j = n & 255;

    // camera dir (uniform across the wave)
    const float cx = (1.0f + (float)j * (-2.0f/255.0f)) * (1.0f/4.2f);
    const float cy = (1.0f + (float)i * (-2.0f/255.0f)) * (1.0f/4.2f);

    const float* tmb = tm + b*12;
    const float dx = tmb[0]*cx + tmb[1]*cy + tmb[2];
    const float dy = tmb[4]*cx + tmb[5]*cy + tmb[6];
    const float dz = tmb[8]*cx + tmb[9]*cy + tmb[10];
    const float ox = tmb[3], oy = tmb[7], oz = tmb[11];

    float bA[4], sA[4];   // feat[c]*(-log2e) = bA[c] + d*sA[c]
    #pragma unroll
    for (int c = 0; c < 4; c++) {
        float s  = dx*wq[0*4+c] + dy*wq[1*4+c] + dz*wq[2*4+c];
        float bb = ox*wq[0*4+c] + oy*wq[1*4+c] + oz*wq[2*4+c]
                 + dx*wq[3*4+c] + dy*wq[4*4+c] + dz*wq[5*4+c];
        sA[c] = s * NL2E;
        bA[c] = bb * NL2E;
    }

    // ---- phase 1: coarse point p = lane ----
    const float dA = 0.1f + (float)lane * STEPV;
    const float opA = sig_pm(bA[0] + dA*sA[0]);
    const float v0A = sig_pm(bA[1] + dA*sA[1]);
    const float v1A = sig_pm(bA[2] + dA*sA[2]);
    const float v2A = sig_pm(bA[3] + dA*sA[3]);

    const float PAi = scan_mul_incl(1.0f - opA, lane);       // prod_{q<=p}(1-op)
    float PAe = __shfl_up(PAi, 1, 64);                       // exclusive
    if (lane == 0) PAe = 1.0f;
    const float wA = opA * PAe;
    const float wt = wA + 1e-5f;

    const float S  = wave_sum(wt);
    const float a0 = wave_sum(wA * v0A);
    const float a1 = wave_sum(wA * v1A);
    const float a2 = wave_sum(wA * v2A);

    const float cdf = scan_add_incl(wt, lane) * __builtin_amdgcn_rcpf(S);

    // ---- phase 2: bin_{lane+1} via searchsorted(cdf, u, side='right') ----
    const float u = (float)(lane + 1) * 0.015625f;           // exact k/64
    const float c63 = __shfl(cdf, 63, 64);
    int lo = 0;
    #pragma unroll
    for (int s = 32; s >= 1; s >>= 1) {                      // probes <= idx 62
        float c = __shfl(cdf, lo + s - 1, 64);
        if (c <= u) lo += s;
    }
    const int ind = (c63 <= u) ? 64 : lo;                    // full count incl. 64-case
    const int below = min(max(ind - 1, 0), 63);
    const int above = min(ind, 63);
    const float c0 = __shfl(cdf, below, 64);
    const float c1 = __shfl(cdf, above, 64);
    const float d0 = 0.1f + (float)below * STEPV;
    const float d1 = 0.1f + (float)above * STEPV;
    float den = c1 - c0;
    den = (den < 1e-8f) ? 1.0f : den;                        // matches ref guard
    float t = (u - c0) * __builtin_amdgcn_rcpf(den);
    t = fminf(fmaxf(t, 0.0f), 1.0f);
    const float binc = d0 + t * (d1 - d0);                   // bin_{lane+1}
    float binp = __shfl_up(binc, 1, 64);
    if (lane == 0) binp = 0.1f;                              // bin_0 == NEAR always
    const float dB = 0.5f * (binp + binc);                   // fine depth k = lane

    // ---- phase 3: fine march = merge-rank decomposition ----
    const float opB = sig_pm(bA[0] + dB*sA[0]);
    const float v0B = sig_pm(bA[1] + dB*sA[1]);
    const float v1B = sig_pm(bA[2] + dB*sA[2]);
    const float v2B = sig_pm(bA[3] + dB*sA[3]);

    const float PBi = scan_mul_incl(1.0f - opB, lane);
    float PBe = __shfl_up(PBi, 1, 64);
    if (lane == 0) PBe = 1.0f;

    // jA = #{p: d_p <= dB}  (A-elements preceding fine point k; ties -> coarse first)
    int ja = 0;
    #pragma unroll
    for (int s = 32; s >= 1; s >>= 1) {
        float dp = 0.1f + (float)(ja + s - 1) * STEPV;
        if (dp <= dB) ja += s;
    }
    const float d63v = 0.1f + 63.0f * STEPV;
    const int jA = (d63v <= dB) ? 64 : ja;

    // jB = #{k: fdep_k < d_A}  (strict; B-elements preceding coarse point p)
    const float f63 = __shfl(dB, 63, 64);
    int jb = 0;
    #pragma unroll
    for (int s = 32; s >= 1; s >>= 1) {
        float f = __shfl(dB, jb + s - 1, 64);
        if (f < dA) jb += s;
    }
    const int jB = (f63 < dA) ? 64 : jb;

    float PBg = __shfl(PBi, max(jB - 1, 0), 64);
    if (jB == 0) PBg = 1.0f;
    float PAg = __shfl(PAi, max(jA - 1, 0), 64);
    if (jA == 0) PAg = 1.0f;

    const float w2A = opA * (PAe * PBg);
    const float w2B = opB * (PBe * PAg);

    const float f0 = wave_sum(fmaf(w2A, v0A, w2B * v0B));
    const float f1 = wave_sum(fmaf(w2A, v1A, w2B * v1B));
    const float f2 = wave_sum(fmaf(w2A, v2A, w2B * v2B));
    const float sw = wave_sum(w2A + w2B);
    const float rd = wave_sum(fmaf(w2A, dA, w2B * dB));

    if (lane == 0) {
        out[(b*3+0)*65536 + n] = a0;
        out[(b*3+1)*65536 + n] = a1;
        out[(b*3+2)*65536 + n] = a2;
        out[393216 + (b*3+0)*65536 + n] = f0;
        out[393216 + (b*3+1)*65536 + n] = f1;
        out[393216 + (b*3+2)*65536 + n] = f2;
        float fop = fminf(fmaxf(sw, 0.0f), 1.0f);
        out[786432 + r] = rd + (1.0f - fop) * 2.0f;          // d_all.max()==2.0 exactly
    }
}

// single-block min/max over the 131072 raw depths -> no atomics, no memset init
__global__ __launch_bounds__(1024) void reduce_mm(const float* __restrict__ out,
                                                  float* __restrict__ mmx)
{
    __shared__ float smn[16], smx[16];
    const int tid = threadIdx.x;
    float mn = 3.4e38f, mx = -3.4e38f;
    for (int idx = tid; idx < NRAYS; idx += 1024) {
        float v = out[786432 + idx];
        mn = fminf(mn, v);
        mx = fmaxf(mx, v);
    }
    #pragma unroll
    for (int m = 32; m >= 1; m >>= 1) {
        mn = fminf(mn, __shfl_xor(mn, m, 64));
        mx = fmaxf(mx, __shfl_xor(mx, m, 64));
    }
    if ((tid & 63) == 0) { smn[tid >> 6] = mn; smx[tid >> 6] = mx; }
    __syncthreads();
    if (tid == 0) {
        float a = smn[0], c = smx[0];
        #pragma unroll
        for (int k = 1; k < 16; k++) { a = fminf(a, smn[k]); c = fmaxf(c, smx[k]); }
        mmx[0] = a;
        mmx[1] = c;
    }
}

__global__ __launch_bounds__(256) void nerf_norm(float* __restrict__ out,
                                                 const float* __restrict__ mmx)
{
    int idx = blockIdx.x * 256 + threadIdx.x;
    float mn = mmx[0], mx = mmx[1];
    float v = out[786432 + idx];
    out[786432 + idx] = (v - mn) * __builtin_amdgcn_rcpf(mx - mn);
}

extern "C" void kernel_launch(void* const* d_in, const int* in_sizes, int n_in,
                              void* d_out, int out_size, void* d_ws, size_t ws_size,
                              hipStream_t stream) {
    (void)in_sizes; (void)n_in; (void)out_size; (void)ws_size;
    const float* tm = (const float*)d_in[0];
    const float* wq = (const float*)d_in[1];
    float* out = (float*)d_out;
    float* mmx = (float*)d_ws;   // fully written by reduce_mm before nerf_norm reads it
    nerf_main<<<NRAYS/4, 256, 0, stream>>>(tm, wq, out);
    reduce_mm<<<1, 1024, 0, stream>>>(out, mmx);
    nerf_norm<<<NRAYS/256, 256, 0, stream>>>(out, mmx);
}

// Round 4
// 140.338 us; speedup vs baseline: 1.5652x; 1.5652x over previous
//
#include <hip/hip_runtime.h>
#include <math.h>

// Thread-per-ray, zero cross-lane comm (R3 showed shuffles cost ~3x), zero
// divergent inner loops (R2 showed ~4x wave-divergence inflation).
// Query is affine in depth: feat[c]*(-log2e) = bA[c] + d*sA[c]; sigmoid =
// rcp(1 + exp2(arg)). Phase 2 = fixed-128-trip branchless two-pointer machine
// (advance cdf segment XOR emit sample per iter; <=64 advances => >=64 emits).
// Fine depths in LDS column fd[k][tid]: bank = tid mod 32 => 2-way = free.
// Row 64 is a junk pad so dead iterations store/load unguarded.

#define NT 128
#define PTS 64
#define NRAYS (2*256*256)
#define NEARV 0.1f
#define STEPV (1.9f/63.0f)
#define FAR63 (0.1f + 63.0f*(1.9f/63.0f))
#define NL2E (-1.4426950408889634f)

extern "C" __device__ float __ocml_native_exp2_f32(float);

__device__ __forceinline__ float sig_pm(float arg) {   // arg is already -x*log2e
    return __builtin_amdgcn_rcpf(1.0f + __ocml_native_exp2_f32(arg));
}

__global__ __launch_bounds__(NT) void nerf_main(
    const float* __restrict__ tm, const float* __restrict__ wq,
    float* __restrict__ out, unsigned int* __restrict__ mmx)
{
    __shared__ float fd[PTS + 1][NT];      // +1 junk pad row
    const int tid = threadIdx.x;
    const int r = blockIdx.x * NT + tid;
    const int b = r >> 16;
    const int n = r & 65535;
    const int i = n >> 8;
    const int j = n & 255;

    const float cx = (1.0f + (float)j * (-2.0f/255.0f)) * (1.0f/4.2f);
    const float cy = (1.0f + (float)i * (-2.0f/255.0f)) * (1.0f/4.2f);

    const float* tmb = tm + b*12;
    const float dx = tmb[0]*cx + tmb[1]*cy + tmb[2];
    const float dy = tmb[4]*cx + tmb[5]*cy + tmb[6];
    const float dz = tmb[8]*cx + tmb[9]*cy + tmb[10];
    const float ox = tmb[3], oy = tmb[7], oz = tmb[11];

    float bA[4], sA[4];
    #pragma unroll
    for (int c = 0; c < 4; c++) {
        float s  = dx*wq[0*4+c] + dy*wq[1*4+c] + dz*wq[2*4+c];
        float bb = ox*wq[0*4+c] + oy*wq[1*4+c] + oz*wq[2*4+c]
                 + dx*wq[3*4+c] + dy*wq[4*4+c] + dz*wq[5*4+c];
        sA[c] = s * NL2E;
        bA[c] = bb * NL2E;
    }

    // ---- phase 1: coarse march (uniform 64-trip loop) ----
    float T = 1.0f, S = 0.0f, a0 = 0.0f, a1 = 0.0f, a2 = 0.0f;
    #pragma unroll 8
    for (int p = 0; p < PTS; p++) {
        float d  = NEARV + (float)p * STEPV;
        float op = sig_pm(bA[0] + d*sA[0]);
        float v0 = sig_pm(bA[1] + d*sA[1]);
        float v1 = sig_pm(bA[2] + d*sA[2]);
        float v2 = sig_pm(bA[3] + d*sA[3]);
        float w  = op * T;
        a0 += w*v0; a1 += w*v1; a2 += w*v2;
        S  += w + 1e-5f;
        T  *= (1.0f - op);
    }
    out[(b*3+0)*65536 + n] = a0;
    out[(b*3+1)*65536 + n] = a1;
    out[(b*3+2)*65536 + n] = a2;

    // ---- phase 2: branchless sampling machine, fixed 128 trips ----
    // state: ind (c_hi = cdf[ind], c_lo = cdf[ind-1]), T2, k (next emit), bin_prev
    const float Sinv = __builtin_amdgcn_rcpf(S);
    float op0 = sig_pm(bA[0] + NEARV*sA[0]);
    float T2   = 1.0f - op0;
    float c_lo = 0.0f;
    float c_hi = (op0 + 1e-5f) * Sinv;     // cdf[0]
    int ind = 0, k = 1;
    float bin_prev = NEARV;                // bin_0 == NEAR always (u=0 < cdf[0])
    #pragma unroll 1
    for (int it = 0; it < 2*PTS; it++) {
        float u = (float)k * 0.015625f;    // exact k/64
        bool adv = (ind < PTS) && (c_hi <= u);   // searchsorted 'right' semantics
        // advance-path candidates (segment ind+1)
        float dn  = NEARV + (float)min(ind + 1, 63) * STEPV;
        float opn = sig_pm(bA[0] + dn*sA[0]);
        float wn  = opn * T2;
        // emit-path candidates
        float d0  = NEARV + (float)(ind - 1) * STEPV;
        float den = c_hi - c_lo;
        den = (den < 1e-8f) ? 1.0f : den;  // ref guard
        float t = (u - c_lo) * __builtin_amdgcn_rcpf(den);
        t = fminf(fmaxf(t, 0.0f), 1.0f);
        float bin = d0 + t * STEPV;
        bin = (ind <= 0)   ? NEARV : bin;
        bin = (ind >= PTS) ? FAR63 : bin;
        float fdep = 0.5f * (bin_prev + bin);
        if (adv) {
            ind++; c_lo = c_hi; c_hi = c_hi + (wn + 1e-5f) * Sinv; T2 *= (1.0f - opn);
        } else {
            fd[min(k - 1, PTS)][tid] = fdep;   // k>64 lands in pad row
            bin_prev = bin; k++;
        }
    }

    // ---- phase 3: branchless merge of coarse linspace + LDS fine depths ----
    float T3 = 1.0f, sw = 0.0f, f0 = 0.0f, f1 = 0.0f, f2 = 0.0f, rd = 0.0f;
    int pc = 0, pf = 0;
    float dc  = NEARV;
    float cur = fd[0][tid];                // one-ahead prefetch: cur = fd[pf], nxt = fd[pf+1]
    float nxt = fd[1][tid];
    #pragma unroll 1
    for (int it = 0; it < 2*PTS; it++) {
        float dfv = (pf < PTS) ? cur : 3.0e38f;
        bool tc = (pc < PTS) && (dc <= dfv);           // ties -> coarse (stable argsort)
        float d = tc ? dc : dfv;
        if (tc) {
            pc++; dc = NEARV + (float)pc * STEPV;
        } else {
            pf++; cur = nxt; nxt = fd[min(pf + 1, PTS)][tid];   // pad row when exhausted
        }
        float op = sig_pm(bA[0] + d*sA[0]);
        float v0 = sig_pm(bA[1] + d*sA[1]);
        float v1 = sig_pm(bA[2] + d*sA[2]);
        float v2 = sig_pm(bA[3] + d*sA[3]);
        float w  = op * T3;
        f0 += w*v0; f1 += w*v1; f2 += w*v2;
        sw += w;
        rd += w*d;
        T3 *= (1.0f - op);
    }
    out[393216 + (b*3+0)*65536 + n] = f0;
    out[393216 + (b*3+1)*65536 + n] = f1;
    out[393216 + (b*3+2)*65536 + n] = f2;

    float fop  = fminf(fmaxf(sw, 0.0f), 1.0f);
    float rdep = rd + (1.0f - fop) * 2.0f;   // d_all.max() == 2.0 exactly
    out[786432 + r] = rdep;

    // min/max via u32 atomicMin on (bits, ~bits): one 0xFF memset inits both.
    // rdep > 0 => u32 ordering == float ordering; ~ reverses it.
    unsigned ub = __float_as_uint(rdep);
    unsigned kmn = ub, kmx = ~ub;
    #pragma unroll
    for (int m = 32; m >= 1; m >>= 1) {
        unsigned omn = (unsigned)__shfl_xor((int)kmn, m, 64);
        unsigned omx = (unsigned)__shfl_xor((int)kmx, m, 64);
        kmn = (omn < kmn) ? omn : kmn;
        kmx = (omx < kmx) ? omx : kmx;
    }
    if ((tid & 63) == 0) {
        atomicMin(&mmx[0], kmn);
        atomicMin(&mmx[1], kmx);
    }
}

__global__ __launch_bounds__(256) void nerf_norm(float* __restrict__ out,
                                                 const unsigned int* __restrict__ mmx)
{
    int idx = blockIdx.x * 256 + threadIdx.x;
    float mn = __uint_as_float(mmx[0]);
    float mx = __uint_as_float(~mmx[1]);
    float v = out[786432 + idx];
    out[786432 + idx] = (v - mn) * __builtin_amdgcn_rcpf(mx - mn);
}

extern "C" void kernel_launch(void* const* d_in, const int* in_sizes, int n_in,
                              void* d_out, int out_size, void* d_ws, size_t ws_size,
                              hipStream_t stream) {
    (void)in_sizes; (void)n_in; (void)out_size; (void)ws_size;
    const float* tm = (const float*)d_in[0];
    const float* wq = (const float*)d_in[1];
    float* out = (float*)d_out;
    unsigned int* mmx = (unsigned int*)d_ws;
    hipMemsetAsync(d_ws, 0xFF, 8, stream);   // inits both min-keys to UINT_MAX
    nerf_main<<<NRAYS/NT, NT, 0, stream>>>(tm, wq, out, mmx);
    nerf_norm<<<NRAYS/256, 256, 0, stream>>>(out, mmx);
}